// Round 3
// baseline (90.035 us; speedup 1.0000x reference)
//
#include <hip/hip_runtime.h>
#include <math.h>

#define NG 1024
#define NC 2
#define HH 224
#define WW 224
#define TILES_X 28
#define TILES_Y 28
#define EPS2D 0.3f
#define ALPHA_MIN (1.0f/255.0f)
#define ALPHA_MAX 0.999f
#define MAXL 512
#define LOG2E 1.4426950408889634f

// d_ws layout (bytes; all 16B-aligned). Poisoned every iteration -> every
// byte we read is rewritten by prep/rank each launch.
#define OFF_SA   0                        // float4[NC*NG]   sorted payload A (u,v,iaS,ibS)
#define OFF_SB   (OFF_SA  + NC*NG*16)     // float4[NC*NG]   sorted payload B (idS,o,r,g)
#define OFF_SC   (OFF_SB  + NC*NG*16)     // float [NC*NG]   sorted payload C (b)
#define OFF_SBB  (OFF_SC  + NC*NG*4)      // u32   [NC*NG]   sorted packed tile bbox
#define OFF_KEY  (OFF_SBB + NC*NG*4)      // u64   [NC*NG]   (z_bits<<10)|gid
#define OFF_UA   (OFF_KEY + NC*NG*8)      // unsorted mirrors of SA/SB/SC/SBB
#define OFF_UB   (OFF_UA  + NC*NG*16)
#define OFF_UC   (OFF_UB  + NC*NG*16)
#define OFF_UBB  (OFF_UC  + NC*NG*4)      // end = 180224 B << ws_size

// ---------------- kernel A: once-per-(cam,gaussian) full prep ----------------
// Projection, exact 2D conic, exact alpha>1/255 support bbox (in tile coords),
// composite payload, and the stable sort key. Invalid/empty -> never-match
// bbox + max key (unique via gid) so ranks stay a permutation.
__global__ __launch_bounds__(256) void prep_kernel(
        const float* __restrict__ w2cs, const float* __restrict__ Ks,
        const float* __restrict__ xyz, const float* __restrict__ rgb,
        const float* __restrict__ opac, const float* __restrict__ scale,
        const float* __restrict__ rot, unsigned char* __restrict__ ws) {
    const int cam = blockIdx.y;
    const int g = blockIdx.x * 256 + threadIdx.x;

    const float* vm = w2cs + cam*16;
    const float R00 = vm[0],  R01 = vm[1],  R02 = vm[2],  t0 = vm[3];
    const float R10 = vm[4],  R11 = vm[5],  R12 = vm[6],  t1 = vm[7];
    const float R20 = vm[8],  R21 = vm[9],  R22 = vm[10], t2 = vm[11];
    const float* Kc = Ks + cam*9;
    const float fx = Kc[0], cx = Kc[2], fy = Kc[4], cy = Kc[5];
    const float limx = 1.3f * (0.5f * (float)WW / fx);
    const float limy = 1.3f * (0.5f * (float)HH / fy);

    float qw = rot[g*4+0], qx = rot[g*4+1], qy = rot[g*4+2], qz = rot[g*4+3];
    float qn = rsqrtf(qw*qw + qx*qx + qy*qy + qz*qz);
    qw *= qn; qx *= qn; qy *= qn; qz *= qn;
    float r00 = 1.f - 2.f*(qy*qy + qz*qz), r01 = 2.f*(qx*qy - qw*qz), r02 = 2.f*(qx*qz + qw*qy);
    float r10 = 2.f*(qx*qy + qw*qz), r11 = 1.f - 2.f*(qx*qx + qz*qz), r12 = 2.f*(qy*qz - qw*qx);
    float r20 = 2.f*(qx*qz - qw*qy), r21 = 2.f*(qy*qz + qw*qx), r22 = 1.f - 2.f*(qx*qx + qy*qy);

    float sx = scale[g*3+0], sy = scale[g*3+1], sz = scale[g*3+2];
    float m00 = r00*sx, m01 = r01*sy, m02 = r02*sz;
    float m10 = r10*sx, m11 = r11*sy, m12 = r12*sz;
    float m20 = r20*sx, m21 = r21*sy, m22 = r22*sz;
    float c00 = m00*m00 + m01*m01 + m02*m02;
    float c01 = m00*m10 + m01*m11 + m02*m12;
    float c02 = m00*m20 + m01*m21 + m02*m22;
    float c11 = m10*m10 + m11*m11 + m12*m12;
    float c12 = m10*m20 + m11*m21 + m12*m22;
    float c22 = m20*m20 + m21*m21 + m22*m22;

    float X = xyz[g*3], Y = xyz[g*3+1], Z = xyz[g*3+2];
    float px = R00*X + R01*Y + R02*Z + t0;
    float py = R10*X + R11*Y + R12*Z + t1;
    float pz = R20*X + R21*Y + R22*Z + t2;
    float rz = 1.f / pz;

    float txc = pz * fminf(fmaxf(px*rz, -limx), limx);
    float tyc = pz * fminf(fmaxf(py*rz, -limy), limy);

    float v00 = R00*c00 + R01*c01 + R02*c02;
    float v01 = R00*c01 + R01*c11 + R02*c12;
    float v02 = R00*c02 + R01*c12 + R02*c22;
    float v10 = R10*c00 + R11*c01 + R12*c02;
    float v11 = R10*c01 + R11*c11 + R12*c12;
    float v12 = R10*c02 + R11*c12 + R12*c22;
    float v20 = R20*c00 + R21*c01 + R22*c02;
    float v21 = R20*c01 + R21*c11 + R22*c12;
    float v22 = R20*c02 + R21*c12 + R22*c22;
    float cc00 = v00*R00 + v01*R01 + v02*R02;
    float cc01 = v00*R10 + v01*R11 + v02*R12;
    float cc02 = v00*R20 + v01*R21 + v02*R22;
    float cc11 = v10*R10 + v11*R11 + v12*R12;
    float cc12 = v10*R20 + v11*R21 + v12*R22;
    float cc22 = v20*R20 + v21*R21 + v22*R22;

    float j00 = fx*rz, j02 = -fx*txc*rz*rz;
    float j11 = fy*rz, j12 = -fy*tyc*rz*rz;
    float a  = j00*j00*cc00 + 2.f*j00*j02*cc02 + j02*j02*cc22 + EPS2D;
    float bq = j00*j11*cc01 + j00*j12*cc02 + j02*j11*cc12 + j02*j12*cc22;
    float d  = j11*j11*cc11 + 2.f*j11*j12*cc12 + j12*j12*cc22 + EPS2D;
    float det = a*d - bq*bq;

    float o = opac[g];
    float tau = __logf(255.f * o);
    bool valid = (pz > 0.01f) && (pz < 100.f) && (det > 0.f) && (tau > 0.f);

    float4 A4 = make_float4(0.f, 0.f, 0.f, 0.f);
    float4 B4 = make_float4(0.f, 0.f, 0.f, 0.f);
    float  C1 = 0.f;
    unsigned bb = 0xFFFFFFFFu;   // tx0=255 > TX: never matches any tile
    unsigned long long key = (0xFFFFFFFFull << 10) | (unsigned)g;  // sorts last, unique

    if (valid) {
        // exact support bbox of {alpha > 1/255} = {sigma <= tau}:
        // half-extents sqrt(2*tau*Sigma'_xx), sqrt(2*tau*Sigma'_yy) (+margin)
        float hx = sqrtf(2.f*tau*a) + 0.02f;
        float hy = sqrtf(2.f*tau*d) + 0.02f;
        float uu = fx*px*rz + cx;
        float vv = fy*py*rz + cy;
        int xmin = max((int)ceilf (uu - hx - 0.5f), 0);
        int xmax = min((int)floorf(uu + hx - 0.5f), WW-1);
        int ymin = max((int)ceilf (vv - hy - 0.5f), 0);
        int ymax = min((int)floorf(vv + hy - 0.5f), HH-1);
        if (xmin <= xmax && ymin <= ymax) {
            bb = (unsigned)(xmin>>3) | ((unsigned)(xmax>>3)<<8)
               | ((unsigned)(ymin>>3)<<16) | ((unsigned)(ymax>>3)<<24);
            float idet = 1.f / det;
            A4 = make_float4(uu, vv, 0.5f*LOG2E*d*idet, -LOG2E*bq*idet);
            B4 = make_float4(0.5f*LOG2E*a*idet, o, rgb[g*3+0], rgb[g*3+1]);
            C1 = rgb[g*3+2];
            key = ((unsigned long long)__float_as_uint(pz) << 10) | (unsigned)g;
        }
    }

    const int idx = cam*NG + g;
    ((float4*)(ws + OFF_UA))[idx] = A4;
    ((float4*)(ws + OFF_UB))[idx] = B4;
    ((float*) (ws + OFF_UC))[idx] = C1;
    ((unsigned*)(ws + OFF_UBB))[idx] = bb;
    ((unsigned long long*)(ws + OFF_KEY))[idx] = key;
}

// ---------------- kernel B: global rank sort + payload scatter ----------------
// Keys unique (gid in low bits) -> ranks are a permutation; ascending
// (z_bits, gid) == jnp.argsort(z) stable order for positive z.
__global__ __launch_bounds__(256) void rank_kernel(unsigned char* __restrict__ ws) {
    const int cam = blockIdx.y;
    __shared__ unsigned long long kl[NG];
    const unsigned long long* keyU = (const unsigned long long*)(ws + OFF_KEY) + cam*NG;
    for (int i = threadIdx.x; i < NG; i += 256) kl[i] = keyU[i];
    __syncthreads();

    const int g = blockIdx.x * 256 + threadIdx.x;
    const unsigned long long myk = kl[g];
    int r = 0;
    #pragma unroll 8
    for (int j = 0; j < NG; j++) r += (kl[j] < myk) ? 1 : 0;

    const int src = cam*NG + g, dst = cam*NG + r;
    ((float4*)(ws + OFF_SA))[dst] = ((const float4*)(ws + OFF_UA))[src];
    ((float4*)(ws + OFF_SB))[dst] = ((const float4*)(ws + OFF_UB))[src];
    ((float*) (ws + OFF_SC))[dst] = ((const float*) (ws + OFF_UC))[src];
    ((unsigned*)(ws + OFF_SBB))[dst] = ((const unsigned*)(ws + OFF_UBB))[src];
}

// ---------------- kernel C: per-tile scan + compact + composite ----------------
__global__ __launch_bounds__(256) void render_kernel(
        const unsigned char* __restrict__ ws, float* __restrict__ out) {
    const int cam = blockIdx.z;
    const int TX = blockIdx.x, TY = blockIdx.y;
    const int tid = threadIdx.x;
    const int lane = tid & 63;
    const int wv   = tid >> 6;

    __shared__ float4 sA[MAXL];
    __shared__ float4 sB[MAXL];
    __shared__ float  sC[MAXL];
    // list consumed by the stage loop (before its barrier); part written after.
    __shared__ union Sh {
        unsigned short list[MAXL];   // 1024 B
        float4 part[4][64];          // 4096 B
    } shu;
    __shared__ int cnt[16];

    // scan 1024 sorted bboxes: 4 coalesced u32 tests per thread
    const unsigned* bbs = (const unsigned*)(ws + OFF_SBB) + cam*NG;
    bool cd[4];
    #pragma unroll
    for (int k = 0; k < 4; k++) {
        unsigned b = bbs[k*256 + tid];
        int tx0 = (int)(b & 255u), tx1 = (int)((b>>8) & 255u);
        int ty0 = (int)((b>>16) & 255u), ty1 = (int)(b>>24);
        cd[k] = (TX >= tx0) && (TX <= tx1) && (TY >= ty0) && (TY <= ty1);
        unsigned long long m = __ballot(cd[k]);
        if (lane == 0) cnt[k*4 + wv] = __popcll(m);
    }
    __syncthreads();

    // order-preserving compaction: global order = (chunk k, wave wv, lane)
    // == sorted-position order, so the list is already depth-sorted.
    int baseK[4], run = 0;
    #pragma unroll
    for (int s = 0; s < 16; s++) {
        if ((s & 3) == wv) baseK[s >> 2] = run;
        run += cnt[s];
    }
    int n2 = min(run, MAXL);
    const unsigned long long lt = (1ull << lane) - 1ull;
    #pragma unroll
    for (int k = 0; k < 4; k++) {
        unsigned long long m = __ballot(cd[k]);
        if (cd[k]) {
            int pos = baseK[k] + __popcll(m & lt);
            if (pos < MAXL) shu.list[pos] = (unsigned short)(k*256 + tid);
        }
    }
    __syncthreads();

    if (n2 == 0) {   // uniform per block: bg-only fast path
        if (tid < 64) {
            int p = (TY*8 + (lane >> 3)) * WW + TX*8 + (lane & 7);
            float* img = out + (size_t)cam * (HH*WW*3) + (size_t)p * 3;
            img[0] = 1.f; img[1] = 1.f; img[2] = 1.f;
            out[(size_t)NC*HH*WW*3 + (size_t)cam*(HH*WW) + p] = 0.f;
        }
        return;
    }

    // gather-stage the tile's (sorted) payloads from L2 into LDS
    const float4* gA = (const float4*)(ws + OFF_SA) + cam*NG;
    const float4* gB = (const float4*)(ws + OFF_SB) + cam*NG;
    const float*  gC = (const float*) (ws + OFF_SC) + cam*NG;
    for (int i = tid; i < n2; i += 256) {
        int p = shu.list[i];
        sA[i] = gA[p];
        sB[i] = gB[p];
        sC[i] = gC[p];
    }
    __syncthreads();

    // depth-segmented composite (wave wv = depth segment wv)
    const float pxl = (float)(TX*8 + (lane & 7)) + 0.5f;
    const float pyl = (float)(TY*8 + (lane >> 3)) + 0.5f;
    int seglen = (n2 + 3) >> 2;
    int js = wv * seglen;
    int je = min(n2, js + seglen);

    float T = 1.f, cr = 0.f, cg = 0.f, cb = 0.f;
#define CBODY(J) do { \
        float4 ga = sA[J]; float4 gb = sB[J]; float bv = sC[J]; \
        float dx = ga.x - pxl, dy = ga.y - pyl; \
        float sg = ga.z*dx*dx + gb.x*dy*dy + ga.w*dx*dy; \
        float al = fminf(gb.y * exp2f(-sg), ALPHA_MAX); \
        al = (sg >= 0.f && al > ALPHA_MIN) ? al : 0.f; \
        float wgt = al * T; \
        cr += wgt * gb.z; cg += wgt * gb.w; cb += wgt * bv; \
        T -= al * T; \
    } while (0)

    int j = js;
    while (j + 16 <= je) {
        #pragma unroll 4
        for (int q = 0; q < 16; q++) { CBODY(j + q); }
        j += 16;
        if (__all(T < 1e-4f)) break;
    }
    for (; j < je; j++) { CBODY(j); }
#undef CBODY

    shu.part[wv][lane] = make_float4(cr, cg, cb, T);
    __syncthreads();

    if (tid < 64) {
        float4 c0 = shu.part[0][lane];
        float Cr = c0.x, Cg = c0.y, Cb = c0.z, Tp = c0.w;
        #pragma unroll
        for (int s = 1; s < 4; s++) {
            float4 cs = shu.part[s][lane];
            Cr += Tp * cs.x;
            Cg += Tp * cs.y;
            Cb += Tp * cs.z;
            Tp *= cs.w;
        }
        int p = (TY*8 + (lane >> 3)) * WW + TX*8 + (lane & 7);
        float* img = out + (size_t)cam * (HH*WW*3) + (size_t)p * 3;
        img[0] = Cr + Tp;           // bg = (1,1,1)
        img[1] = Cg + Tp;
        img[2] = Cb + Tp;
        out[(size_t)NC*HH*WW*3 + (size_t)cam*(HH*WW) + p] = 1.f - Tp;
    }
}

extern "C" void kernel_launch(void* const* d_in, const int* in_sizes, int n_in,
                              void* d_out, int out_size, void* d_ws, size_t ws_size,
                              hipStream_t stream) {
    const float* w2cs  = (const float*)d_in[0];
    const float* Ks    = (const float*)d_in[1];
    const float* xyz   = (const float*)d_in[2];
    const float* rgb   = (const float*)d_in[3];
    const float* opac  = (const float*)d_in[4];
    const float* scale = (const float*)d_in[5];
    const float* rot   = (const float*)d_in[6];
    unsigned char* ws = (unsigned char*)d_ws;
    float* out = (float*)d_out;

    prep_kernel  <<<dim3(4, NC),               256, 0, stream>>>(w2cs, Ks, xyz, rgb, opac, scale, rot, ws);
    rank_kernel  <<<dim3(4, NC),               256, 0, stream>>>(ws);
    render_kernel<<<dim3(TILES_X, TILES_Y, NC), 256, 0, stream>>>(ws, out);
}

// Round 4
// 83.387 us; speedup vs baseline: 1.0797x; 1.0797x over previous
//
#include <hip/hip_runtime.h>
#include <math.h>

#define NG 1024
#define NC 2
#define HH 224
#define WW 224
#define TILES_X 28
#define TILES_Y 28
#define EPS2D 0.3f
#define ALPHA_MIN (1.0f/255.0f)
#define ALPHA_MAX 0.999f
#define MAXL 512
#define LOG2E 1.4426950408889634f

// Single dispatch (dispatch count is first-order in this harness: 1->3
// dispatches cost +12us measured). Per 8x8-pixel tile block:
//  1) per-gaussian: cheap gate -> conservative float gate (superset of exact)
//     -> divergent full prep -> EXACT alpha>1/255 support-bbox tile test.
//     Survivors' payloads+keys ballot-compacted into unsorted LDS slots.
//  2) rank sort, wave-0 only: wave 0 keeps all <=512 slot keys in registers
//     (8/lane) and makes ONE pass over the n keys (LDS traffic /4 vs all-wave
//     scan), compare width sized to ceil(n/64) via uniform branches. Ranks
//     are a permutation (keys unique: gid in low bits). Ascending (z_bits,
//     gid) == reference's stable argsort(z) restricted to contributors.
//  3) in-place payload permutation: every thread reads its <=2 slots to regs,
//     barrier, writes to rank position.
//  4) 4 depth-segment waves composite (conic pre-scaled by 0.5*log2e ->
//     exp2) + associative (C,T) merge. Empty tiles exit early after step 1.
__global__ __launch_bounds__(256) void fused_kernel(
        const float* __restrict__ w2cs, const float* __restrict__ Ks,
        const float* __restrict__ xyz, const float* __restrict__ rgb,
        const float* __restrict__ opac, const float* __restrict__ scale,
        const float* __restrict__ rot, float* __restrict__ out) {
    const int cam = blockIdx.z;
    const int TX = blockIdx.x, TY = blockIdx.y;
    const int tid = threadIdx.x;
    const int lane = tid & 63;
    const int wv   = tid >> 6;

    __shared__ float4 sA[MAXL];          // u, v, ia*0.5*log2e, ib*log2e
    __shared__ float4 sB[MAXL];          // id*0.5*log2e, o, r, g
    __shared__ float  sC[MAXL];          // b (blue)
    // keys last read in phase 2; part first written after composite.
    __shared__ union {
        unsigned long long keys[MAXL];   // 4096 B
        float4 part[4][64];              // 4096 B
    } shu;
    __shared__ unsigned short rank16[MAXL];
    __shared__ int scnt;

    if (tid == 0) scnt = 0;
    __syncthreads();

    const float* vm = w2cs + cam*16;
    const float R00 = vm[0],  R01 = vm[1],  R02 = vm[2],  t0 = vm[3];
    const float R10 = vm[4],  R11 = vm[5],  R12 = vm[6],  t1 = vm[7];
    const float R20 = vm[8],  R21 = vm[9],  R22 = vm[10], t2 = vm[11];
    const float* Kc = Ks + cam*9;
    const float fx = Kc[0], cx = Kc[2], fy = Kc[4], cy = Kc[5];
    const float limx = 1.3f * (0.5f * (float)WW / fx);
    const float limy = 1.3f * (0.5f * (float)HH / fy);

    const float xlo = (float)(TX*8) + 0.5f, xhi = (float)(TX*8) + 7.5f;
    const float ylo = (float)(TY*8) + 0.5f, yhi = (float)(TY*8) + 7.5f;

    // ---- phase 1: exact prep + cull + compaction ----
    for (int k = 0; k < 4; k++) {
        int g = k*256 + tid;
        float X = xyz[g*3], Y = xyz[g*3+1], Z = xyz[g*3+2];
        float pz = R20*X + R21*Y + R22*Z + t2;
        float o  = opac[g];
        float tau = __logf(255.f * o);
        bool cand = (pz > 0.01f) && (pz < 100.f) && (tau > 0.f);
        bool pass = false;
        float4 A4, B4; float C1 = 0.f;
        if (cand) {
            float rz = 1.f / pz;
            float px = R00*X + R01*Y + R02*Z + t0;
            float py = R10*X + R11*Y + R12*Z + t1;
            float uu = fx*px*rz + cx;
            float vv = fy*py*rz + cy;
            float sx = scale[g*3+0], sy = scale[g*3+1], sz = scale[g*3+2];
            float smax = fmaxf(sx, fmaxf(sy, sz));
            float j00 = fx*rz, j11 = fy*rz;
            float j02m = fx*limx*rz, j12m = fy*limy*rz;   // |j02| <= j02m
            // lambda_max(Sigma3d) <= smax^2 -> abnd >= exact a, dbnd >= exact d;
            // +0.03 margin > exact path's +0.02 -> strict superset of exact pass
            float abnd = smax*smax*(j00*j00 + j02m*j02m) + EPS2D;
            float dbnd = smax*smax*(j11*j11 + j12m*j12m) + EPS2D;
            float rx = sqrtf(2.f*tau*abnd) + 0.03f;
            float ry = sqrtf(2.f*tau*dbnd) + 0.03f;
            bool cand2 = (uu + rx >= xlo) && (uu - rx <= xhi) &&
                         (vv + ry >= ylo) && (vv - ry <= yhi);
            if (cand2) {
                float qw = rot[g*4+0], qx = rot[g*4+1], qy = rot[g*4+2], qz = rot[g*4+3];
                float qn = rsqrtf(qw*qw + qx*qx + qy*qy + qz*qz);
                qw *= qn; qx *= qn; qy *= qn; qz *= qn;
                float r00 = 1.f - 2.f*(qy*qy + qz*qz), r01 = 2.f*(qx*qy - qw*qz), r02 = 2.f*(qx*qz + qw*qy);
                float r10 = 2.f*(qx*qy + qw*qz), r11 = 1.f - 2.f*(qx*qx + qz*qz), r12 = 2.f*(qy*qz - qw*qx);
                float r20 = 2.f*(qx*qz - qw*qy), r21 = 2.f*(qy*qz + qw*qx), r22 = 1.f - 2.f*(qx*qx + qy*qy);

                float m00 = r00*sx, m01 = r01*sy, m02 = r02*sz;
                float m10 = r10*sx, m11 = r11*sy, m12 = r12*sz;
                float m20 = r20*sx, m21 = r21*sy, m22 = r22*sz;
                float c00 = m00*m00 + m01*m01 + m02*m02;
                float c01 = m00*m10 + m01*m11 + m02*m12;
                float c02 = m00*m20 + m01*m21 + m02*m22;
                float c11 = m10*m10 + m11*m11 + m12*m12;
                float c12 = m10*m20 + m11*m21 + m12*m22;
                float c22 = m20*m20 + m21*m21 + m22*m22;

                float txc = pz * fminf(fmaxf(px*rz, -limx), limx);
                float tyc = pz * fminf(fmaxf(py*rz, -limy), limy);

                float v00 = R00*c00 + R01*c01 + R02*c02;
                float v01 = R00*c01 + R01*c11 + R02*c12;
                float v02 = R00*c02 + R01*c12 + R02*c22;
                float v10 = R10*c00 + R11*c01 + R12*c02;
                float v11 = R10*c01 + R11*c11 + R12*c12;
                float v12 = R10*c02 + R11*c12 + R12*c22;
                float v20 = R20*c00 + R21*c01 + R22*c02;
                float v21 = R20*c01 + R21*c11 + R22*c12;
                float v22 = R20*c02 + R21*c12 + R22*c22;
                float cc00 = v00*R00 + v01*R01 + v02*R02;
                float cc01 = v00*R10 + v01*R11 + v02*R12;
                float cc02 = v00*R20 + v01*R21 + v02*R22;
                float cc11 = v10*R10 + v11*R11 + v12*R12;
                float cc12 = v10*R20 + v11*R21 + v12*R22;
                float cc22 = v20*R20 + v21*R21 + v22*R22;

                float j02 = -fx*txc*rz*rz;
                float j12 = -fy*tyc*rz*rz;
                float a  = j00*j00*cc00 + 2.f*j00*j02*cc02 + j02*j02*cc22 + EPS2D;
                float bq = j00*j11*cc01 + j00*j12*cc02 + j02*j11*cc12 + j02*j12*cc22;
                float d  = j11*j11*cc11 + 2.f*j11*j12*cc12 + j12*j12*cc22 + EPS2D;
                float det = a*d - bq*bq;

                if (det > 0.f) {
                    // exact support bbox of {alpha > 1/255} = {sigma <= tau}:
                    // half-extents sqrt(2*tau*a), sqrt(2*tau*d) (+margin)
                    float hx = sqrtf(2.f*tau*a) + 0.02f;
                    float hy = sqrtf(2.f*tau*d) + 0.02f;
                    int xmin = max((int)ceilf (uu - hx - 0.5f), 0);
                    int xmax = min((int)floorf(uu + hx - 0.5f), WW-1);
                    int ymin = max((int)ceilf (vv - hy - 0.5f), 0);
                    int ymax = min((int)floorf(vv + hy - 0.5f), HH-1);
                    pass = (xmin <= xmax) && (ymin <= ymax) &&
                           (TX >= (xmin>>3)) && (TX <= (xmax>>3)) &&
                           (TY >= (ymin>>3)) && (TY <= (ymax>>3));
                    if (pass) {
                        float idet = 1.f / det;
                        A4 = make_float4(uu, vv, 0.5f*LOG2E*d*idet, -LOG2E*bq*idet);
                        B4 = make_float4(0.5f*LOG2E*a*idet, o, rgb[g*3+0], rgb[g*3+1]);
                        C1 = rgb[g*3+2];
                    }
                }
            }
        }
        unsigned long long m = __ballot(pass);
        int cw = __popcll(m);
        if (cw) {
            int basepos = 0;
            if (lane == 0) basepos = atomicAdd(&scnt, cw);
            basepos = __shfl(basepos, 0);
            if (pass) {
                int pos = basepos + __popcll(m & ((1ull << lane) - 1ull));
                if (pos < MAXL) {
                    shu.keys[pos] = ((unsigned long long)__float_as_uint(pz) << 10)
                                  | (unsigned long long)g;
                    sA[pos] = A4; sB[pos] = B4; sC[pos] = C1;
                }
            }
        }
    }
    __syncthreads();
    const int n = min(scnt, MAXL);

    if (n == 0) {   // uniform: bg-only fast path
        if (tid < 64) {
            int p = (TY*8 + (lane >> 3)) * WW + TX*8 + (lane & 7);
            float* img = out + (size_t)cam * (HH*WW*3) + (size_t)p * 3;
            img[0] = 1.f; img[1] = 1.f; img[2] = 1.f;
            out[(size_t)NC*HH*WW*3 + (size_t)cam*(HH*WW) + p] = 0.f;
        }
        return;
    }

    // ---- phase 2: wave-0 rank computation (keys in regs, one LDS pass) ----
    if (wv == 0) {
        const int nq = (n + 63) >> 6;        // 1..8 key-groups of 64 slots
        unsigned long long myk[8];
        int rk[8];
        #pragma unroll
        for (int q = 0; q < 8; q++) { myk[q] = ~0ull; rk[q] = 0; }
        #pragma unroll
        for (int q = 0; q < 8; q++) {
            int s = q*64 + lane;
            if (q < nq && s < n) myk[q] = shu.keys[s];
        }
        if (nq <= 2) {
            for (int j = 0; j < n; j++) {
                unsigned long long kj = shu.keys[j];
                rk[0] += (kj < myk[0]) ? 1 : 0;
                rk[1] += (kj < myk[1]) ? 1 : 0;
            }
        } else if (nq <= 4) {
            for (int j = 0; j < n; j++) {
                unsigned long long kj = shu.keys[j];
                #pragma unroll
                for (int q = 0; q < 4; q++) rk[q] += (kj < myk[q]) ? 1 : 0;
            }
        } else {
            for (int j = 0; j < n; j++) {
                unsigned long long kj = shu.keys[j];
                #pragma unroll
                for (int q = 0; q < 8; q++) rk[q] += (kj < myk[q]) ? 1 : 0;
            }
        }
        #pragma unroll
        for (int q = 0; q < 8; q++) {
            int s = q*64 + lane;
            if (s < n) rank16[s] = (unsigned short)rk[q];
        }
    }
    // all threads (incl. wave 0 after ranking): stage own slots to regs
    float4 tA0, tB0, tA1, tB1; float tC0 = 0.f, tC1 = 0.f;
    const bool h0 = tid < n, h1 = tid + 256 < n;
    if (h0) { tA0 = sA[tid];     tB0 = sB[tid];     tC0 = sC[tid];     }
    if (h1) { tA1 = sA[tid+256]; tB1 = sB[tid+256]; tC1 = sC[tid+256]; }
    __syncthreads();      // ranks visible; all payload reads complete

    // ---- phase 3: in-place permutation to sorted slots ----
    if (h0) { int r = rank16[tid];     sA[r] = tA0; sB[r] = tB0; sC[r] = tC0; }
    if (h1) { int r = rank16[tid+256]; sA[r] = tA1; sB[r] = tB1; sC[r] = tC1; }
    __syncthreads();

    // ---- phase 4: depth-segmented composite (wave wv = segment wv) ----
    const float pxl = (float)(TX*8 + (lane & 7)) + 0.5f;
    const float pyl = (float)(TY*8 + (lane >> 3)) + 0.5f;
    int seglen = (n + 3) >> 2;
    int js = wv * seglen;
    int je = min(n, js + seglen);

    float T = 1.f, cr = 0.f, cg = 0.f, cb = 0.f;
#define CBODY(J) do { \
        float4 ga = sA[J]; float4 gb = sB[J]; float bv = sC[J]; \
        float dx = ga.x - pxl, dy = ga.y - pyl; \
        float sg = ga.z*dx*dx + gb.x*dy*dy + ga.w*dx*dy; \
        float al = fminf(gb.y * exp2f(-sg), ALPHA_MAX); \
        al = (sg >= 0.f && al > ALPHA_MIN) ? al : 0.f; \
        float wgt = al * T; \
        cr += wgt * gb.z; cg += wgt * gb.w; cb += wgt * bv; \
        T -= al * T; \
    } while (0)

    int j = js;
    while (j + 16 <= je) {
        #pragma unroll 4
        for (int q = 0; q < 16; q++) { CBODY(j + q); }
        j += 16;
        if (__all(T < 1e-4f)) break;
    }
    for (; j < je; j++) { CBODY(j); }
#undef CBODY

    shu.part[wv][lane] = make_float4(cr, cg, cb, T);
    __syncthreads();

    if (tid < 64) {
        float4 c0 = shu.part[0][lane];
        float Cr = c0.x, Cg = c0.y, Cb = c0.z, Tp = c0.w;
        #pragma unroll
        for (int s = 1; s < 4; s++) {
            float4 cs = shu.part[s][lane];
            Cr += Tp * cs.x;
            Cg += Tp * cs.y;
            Cb += Tp * cs.z;
            Tp *= cs.w;
        }
        int p = (TY*8 + (lane >> 3)) * WW + TX*8 + (lane & 7);
        float* img = out + (size_t)cam * (HH*WW*3) + (size_t)p * 3;
        img[0] = Cr + Tp;           // bg = (1,1,1)
        img[1] = Cg + Tp;
        img[2] = Cb + Tp;
        out[(size_t)NC*HH*WW*3 + (size_t)cam*(HH*WW) + p] = 1.f - Tp;
    }
}

extern "C" void kernel_launch(void* const* d_in, const int* in_sizes, int n_in,
                              void* d_out, int out_size, void* d_ws, size_t ws_size,
                              hipStream_t stream) {
    const float* w2cs  = (const float*)d_in[0];
    const float* Ks    = (const float*)d_in[1];
    const float* xyz   = (const float*)d_in[2];
    const float* rgb   = (const float*)d_in[3];
    const float* opac  = (const float*)d_in[4];
    const float* scale = (const float*)d_in[5];
    const float* rot   = (const float*)d_in[6];
    float* out = (float*)d_out;

    fused_kernel<<<dim3(TILES_X, TILES_Y, NC), 256, 0, stream>>>(
        w2cs, Ks, xyz, rgb, opac, scale, rot, out);
}

// Round 5
// 80.080 us; speedup vs baseline: 1.1243x; 1.0413x over previous
//
#include <hip/hip_runtime.h>
#include <math.h>

#define NG 1024
#define NC 2
#define HH 224
#define WW 224
#define RGX 14     // 16-px-wide regions (2 tiles of 8x8 per block)
#define RGY 28
#define EPS2D 0.3f
#define ALPHA_MIN (1.0f/255.0f)
#define ALPHA_MAX 0.999f
#define MAXL 512
#define LOG2E 1.4426950408889634f

// Single dispatch; 784 blocks, each renders a 16x8 region (2 tiles).
// Cost model (validated over rounds 0-4): per-CU time = blocks/CU x per-wave
// cycles; halving blocks/CU by amortizing the per-block-constant work
// (1024-gaussian scan + sort) over 2 tiles is the main lever.
// Pipeline per block:
//  P1 conservative scan of all 1024 (float region test, margin 0.03 >
//     exact 0.02 -> strict superset), ballot-compact f64 keys + gid.
//     key = (double)z_bits*1024 + gid: exact (<2^42), f64 order ==
//     (z_bits,gid) lexicographic == reference stable argsort(z).
//  P2 rank sort: thread owns slots (tid, tid+256); scans all n keys via
//     double2 broadcast reads; v_cmp_lt_f64 is 1 inst. Ranks are a
//     permutation (gid uniquifies); scatter gid -> gidS[rank].
//  P3 dense prep in sorted order (all 256 threads on packed survivors --
//     R4 showed divergent prep in the scan loses ~5us) + exact-support
//     bbox cull + 2-bit tile mask. Dropped entries contribute exactly 0.
//  P4 order-preserving ballot compact of payload+mask to sorted slots.
//  P5 composite: wave wv -> (tile wv&1, depth-seg wv>>1); wave-uniform
//     mask test skips entries not covering the wave's tile. exp2-folded
//     conic. Early-out every 16.
//  P6 merge 2 segments per pixel (associative (C,T) algebra), write out.
__global__ __launch_bounds__(256, 4) void fused_kernel(
        const float* __restrict__ w2cs, const float* __restrict__ Ks,
        const float* __restrict__ xyz, const float* __restrict__ rgb,
        const float* __restrict__ opac, const float* __restrict__ scale,
        const float* __restrict__ rot, float* __restrict__ out) {
    const int cam = blockIdx.z;
    const int BX = blockIdx.x, TY = blockIdx.y;
    const int tid = threadIdx.x;
    const int lane = tid & 63;
    const int wv   = tid >> 6;

    // keys last read in P2 (before its barrier); part first written in P5.
    __shared__ union {
        double keys[MAXL];           // 4096 B
        float4 part[2][2][64];       // [seg][tile][px] 4096 B
    } shu;
    __shared__ float4 sA[MAXL];      // u, v, ia*0.5*log2e, ib*log2e
    __shared__ float4 sB[MAXL];      // id*0.5*log2e, o, r, g
    __shared__ float  sC[MAXL];      // b (blue)
    __shared__ unsigned short gidA[MAXL];   // slot -> gid (unsorted)
    __shared__ unsigned short gidS[MAXL];   // rank -> gid (sorted)
    __shared__ unsigned char  mk[MAXL];     // sorted-compacted 2-bit tile mask
    __shared__ int cnt[8];
    __shared__ int scnt;

    if (tid == 0) scnt = 0;
    __syncthreads();

    const float* vm = w2cs + cam*16;
    const float R00 = vm[0],  R01 = vm[1],  R02 = vm[2],  t0 = vm[3];
    const float R10 = vm[4],  R11 = vm[5],  R12 = vm[6],  t1 = vm[7];
    const float R20 = vm[8],  R21 = vm[9],  R22 = vm[10], t2 = vm[11];
    const float* Kc = Ks + cam*9;
    const float fx = Kc[0], cx = Kc[2], fy = Kc[4], cy = Kc[5];
    const float limx = 1.3f * (0.5f * (float)WW / fx);
    const float limy = 1.3f * (0.5f * (float)HH / fy);

    const float xlo = (float)(BX*16) + 0.5f, xhi = (float)(BX*16) + 15.5f;
    const float ylo = (float)(TY*8)  + 0.5f, yhi = (float)(TY*8)  + 7.5f;

    // ---- P1: conservative scan + key compaction ----
    #pragma unroll
    for (int k = 0; k < 4; k++) {
        int g = k*256 + tid;
        float X = xyz[g*3], Y = xyz[g*3+1], Z = xyz[g*3+2];
        float pz = R20*X + R21*Y + R22*Z + t2;
        float o  = opac[g];
        float tau = __logf(255.f * o);
        bool cand = (pz > 0.01f) && (pz < 100.f) && (tau > 0.f);
        if (cand) {
            float rz = 1.f / pz;
            float px = R00*X + R01*Y + R02*Z + t0;
            float py = R10*X + R11*Y + R12*Z + t1;
            float uu = fx*px*rz + cx;
            float vv = fy*py*rz + cy;
            float sx = scale[g*3+0], sy = scale[g*3+1], sz = scale[g*3+2];
            float smax = fmaxf(sx, fmaxf(sy, sz));
            float j00 = fx*rz, j11 = fy*rz;
            float j02m = fx*limx*rz, j12m = fy*limy*rz;   // |j02| <= j02m
            // lambda_max(Sigma3d) <= smax^2 -> bounds >= exact a,d;
            // margin 0.03 > exact path's 0.02 -> strict superset.
            float abnd = smax*smax*(j00*j00 + j02m*j02m) + EPS2D;
            float dbnd = smax*smax*(j11*j11 + j12m*j12m) + EPS2D;
            float rx = sqrtf(2.f*tau*abnd) + 0.03f;
            float ry = sqrtf(2.f*tau*dbnd) + 0.03f;
            cand = (uu + rx >= xlo) && (uu - rx <= xhi) &&
                   (vv + ry >= ylo) && (vv - ry <= yhi);
        }
        unsigned long long m = __ballot(cand);
        int cw = __popcll(m);
        if (cw) {
            int basepos = 0;
            if (lane == 0) basepos = atomicAdd(&scnt, cw);
            basepos = __shfl(basepos, 0);
            if (cand) {
                int pos = basepos + __popcll(m & ((1ull << lane) - 1ull));
                if (pos < MAXL) {
                    float pz2 = R20*X + R21*Y + R22*Z + t2;   // same bits
                    shu.keys[pos] = (double)__float_as_uint(pz2) * 1024.0
                                  + (double)g;
                    gidA[pos] = (unsigned short)g;
                }
            }
        }
    }
    __syncthreads();
    const int n = min(scnt, MAXL);

    if (n == 0) {    // uniform: bg-only fast path for both tiles
        if (tid < 128) {
            int ln = tid & 63, lt = tid >> 6;
            int px = BX*16 + lt*8 + (ln & 7), py = TY*8 + (ln >> 3);
            int p = py * WW + px;
            float* img = out + (size_t)cam * (HH*WW*3) + (size_t)p * 3;
            img[0] = 1.f; img[1] = 1.f; img[2] = 1.f;
            out[(size_t)NC*HH*WW*3 + (size_t)cam*(HH*WW) + p] = 0.f;
        }
        return;
    }

    // ---- P2: rank sort (f64 keys, broadcast double2 reads) ----
    const bool h0 = tid < n, h1 = tid + 256 < n;
    double myk0 = h0 ? shu.keys[tid]       : 0.0;
    double myk1 = h1 ? shu.keys[tid + 256] : 0.0;
    int r0 = 0, r1 = 0;
    const int nh = n >> 1;
    const double2* kp2 = reinterpret_cast<const double2*>(shu.keys);
    #pragma unroll 2
    for (int q = 0; q < nh; q++) {
        double2 kj = kp2[q];                 // wave-uniform -> LDS broadcast
        r0 += (kj.x < myk0) ? 1 : 0;  r0 += (kj.y < myk0) ? 1 : 0;
        r1 += (kj.x < myk1) ? 1 : 0;  r1 += (kj.y < myk1) ? 1 : 0;
    }
    if (n & 1) {
        double kj = shu.keys[n-1];
        r0 += (kj < myk0) ? 1 : 0;  r1 += (kj < myk1) ? 1 : 0;
    }
    unsigned short mg0 = h0 ? gidA[tid] : 0, mg1 = h1 ? gidA[tid + 256] : 0;
    if (h0) gidS[r0] = mg0;       // ranks are a permutation of [0,n)
    if (h1) gidS[r1] = mg1;
    __syncthreads();

    // ---- P3: dense prep in sorted order + exact cull + tile mask ----
    auto prep = [&](int i, float4 &A, float4 &B, float &C, int &msk) -> bool {
        if (i >= n) return false;
        int g = (int)gidS[i];

        float qw = rot[g*4+0], qx = rot[g*4+1], qy = rot[g*4+2], qz = rot[g*4+3];
        float qn = rsqrtf(qw*qw + qx*qx + qy*qy + qz*qz);
        qw *= qn; qx *= qn; qy *= qn; qz *= qn;
        float r00 = 1.f - 2.f*(qy*qy + qz*qz), r01 = 2.f*(qx*qy - qw*qz), r02 = 2.f*(qx*qz + qw*qy);
        float r10 = 2.f*(qx*qy + qw*qz), r11 = 1.f - 2.f*(qx*qx + qz*qz), r12 = 2.f*(qy*qz - qw*qx);
        float r20 = 2.f*(qx*qz - qw*qy), r21 = 2.f*(qy*qz + qw*qx), r22 = 1.f - 2.f*(qx*qx + qy*qy);

        float sx = scale[g*3+0], sy = scale[g*3+1], sz = scale[g*3+2];
        float m00 = r00*sx, m01 = r01*sy, m02 = r02*sz;
        float m10 = r10*sx, m11 = r11*sy, m12 = r12*sz;
        float m20 = r20*sx, m21 = r21*sy, m22 = r22*sz;
        float c00 = m00*m00 + m01*m01 + m02*m02;
        float c01 = m00*m10 + m01*m11 + m02*m12;
        float c02 = m00*m20 + m01*m21 + m02*m22;
        float c11 = m10*m10 + m11*m11 + m12*m12;
        float c12 = m10*m20 + m11*m21 + m12*m22;
        float c22 = m20*m20 + m21*m21 + m22*m22;

        float X = xyz[g*3], Y = xyz[g*3+1], Z = xyz[g*3+2];
        float px = R00*X + R01*Y + R02*Z + t0;
        float py = R10*X + R11*Y + R12*Z + t1;
        float pz = R20*X + R21*Y + R22*Z + t2;
        float rz = 1.f / pz;

        float txc = pz * fminf(fmaxf(px*rz, -limx), limx);
        float tyc = pz * fminf(fmaxf(py*rz, -limy), limy);

        float v00 = R00*c00 + R01*c01 + R02*c02;
        float v01 = R00*c01 + R01*c11 + R02*c12;
        float v02 = R00*c02 + R01*c12 + R02*c22;
        float v10 = R10*c00 + R11*c01 + R12*c02;
        float v11 = R10*c01 + R11*c11 + R12*c12;
        float v12 = R10*c02 + R11*c12 + R12*c22;
        float v20 = R20*c00 + R21*c01 + R22*c02;
        float v21 = R20*c01 + R21*c11 + R22*c12;
        float v22 = R20*c02 + R21*c12 + R22*c22;
        float cc00 = v00*R00 + v01*R01 + v02*R02;
        float cc01 = v00*R10 + v01*R11 + v02*R12;
        float cc02 = v00*R20 + v01*R21 + v02*R22;
        float cc11 = v10*R10 + v11*R11 + v12*R12;
        float cc12 = v10*R20 + v11*R21 + v12*R22;
        float cc22 = v20*R20 + v21*R21 + v22*R22;

        float j00 = fx*rz, j02 = -fx*txc*rz*rz;
        float j11 = fy*rz, j12 = -fy*tyc*rz*rz;
        float a  = j00*j00*cc00 + 2.f*j00*j02*cc02 + j02*j02*cc22 + EPS2D;
        float bq = j00*j11*cc01 + j00*j12*cc02 + j02*j11*cc12 + j02*j12*cc22;
        float d  = j11*j11*cc11 + 2.f*j11*j12*cc12 + j12*j12*cc22 + EPS2D;
        float det = a*d - bq*bq;

        if (!((pz > 0.01f) && (pz < 100.f) && (det > 0.f))) return false;

        float o = opac[g];
        float tau = __logf(255.f * o);
        if (!(tau > 0.f)) return false;

        // exact support bbox of {alpha > 1/255} = {sigma <= tau}
        float hx = sqrtf(2.f*tau*a) + 0.02f;
        float hy = sqrtf(2.f*tau*d) + 0.02f;
        float uu = fx*px*rz + cx;
        float vv = fy*py*rz + cy;
        int xmin = max((int)ceilf (uu - hx - 0.5f), 0);
        int xmax = min((int)floorf(uu + hx - 0.5f), WW-1);
        int ymin = max((int)ceilf (vv - hy - 0.5f), 0);
        int ymax = min((int)floorf(vv + hy - 0.5f), HH-1);
        if (xmin > xmax || ymin > ymax) return false;
        int tx0 = xmin >> 3, tx1 = xmax >> 3;
        int ty0 = ymin >> 3, ty1 = ymax >> 3;
        if (TY < ty0 || TY > ty1) return false;
        msk = 0;
        if (2*BX   >= tx0 && 2*BX   <= tx1) msk |= 1;
        if (2*BX+1 >= tx0 && 2*BX+1 <= tx1) msk |= 2;
        if (!msk) return false;

        float idet = 1.f / det;
        A = make_float4(uu, vv, 0.5f*LOG2E*d*idet, -LOG2E*bq*idet);
        B = make_float4(0.5f*LOG2E*a*idet, o, rgb[g*3+0], rgb[g*3+1]);
        C = rgb[g*3+2];
        return true;
    };

    float4 A0, B0, A1, B1; float C0 = 0.f, C1 = 0.f; int m0 = 0, m1 = 0;
    bool kp0 = prep(tid,       A0, B0, C0, m0);
    bool kp1 = prep(tid + 256, A1, B1, C1, m1);

    // ---- P4: order-preserving compaction to sorted slots ----
    unsigned long long bal0 = __ballot(kp0);
    unsigned long long bal1 = __ballot(kp1);
    if (lane == 0) { cnt[wv] = __popcll(bal0); cnt[4 + wv] = __popcll(bal1); }
    __syncthreads();
    int base0 = 0, base1 = 0, n2 = 0;
    #pragma unroll
    for (int s = 0; s < 8; s++) {
        int cs = cnt[s];
        base0 += (s < wv)     ? cs : 0;
        base1 += (s < 4 + wv) ? cs : 0;
        n2 += cs;
    }
    const unsigned long long lt64 = (1ull << lane) - 1ull;
    int d0 = base0 + __popcll(bal0 & lt64);
    int d1 = base1 + __popcll(bal1 & lt64);
    if (kp0) { sA[d0] = A0; sB[d0] = B0; sC[d0] = C0; mk[d0] = (unsigned char)m0; }
    if (kp1) { sA[d1] = A1; sB[d1] = B1; sC[d1] = C1; mk[d1] = (unsigned char)m1; }
    __syncthreads();

    // ---- P5: composite (wave wv -> tile wv&1, depth segment wv>>1) ----
    const int lt = wv & 1, sg = wv >> 1;
    const float pxl = (float)(BX*16 + lt*8 + (lane & 7)) + 0.5f;
    const float pyl = (float)(TY*8 + (lane >> 3)) + 0.5f;
    int seglen = (n2 + 1) >> 1;
    int js = sg * seglen;
    int je = min(n2, js + seglen);

    float T = 1.f, cr = 0.f, cg = 0.f, cb = 0.f;
    #pragma unroll 4
    for (int j = js; j < je; j++) {
        if ((mk[j] >> lt) & 1) {          // wave-uniform branch
            float4 ga = sA[j]; float4 gb = sB[j]; float bv = sC[j];
            float dx = ga.x - pxl, dy = ga.y - pyl;
            float sgm = ga.z*dx*dx + gb.x*dy*dy + ga.w*dx*dy;
            float al = fminf(gb.y * exp2f(-sgm), ALPHA_MAX);
            al = (sgm >= 0.f && al > ALPHA_MIN) ? al : 0.f;
            float wgt = al * T;
            cr += wgt * gb.z; cg += wgt * gb.w; cb += wgt * bv;
            T -= al * T;
        }
        if (((j - js) & 15) == 15 && __all(T < 1e-4f)) break;
    }

    shu.part[sg][lt][lane] = make_float4(cr, cg, cb, T);
    __syncthreads();

    // ---- P6: merge 2 depth segments, write out ----
    if (tid < 128) {
        int ln = tid & 63, t2i = tid >> 6;
        float4 c0 = shu.part[0][t2i][ln];
        float4 c1 = shu.part[1][t2i][ln];
        float Cr = c0.x + c0.w * c1.x;
        float Cg = c0.y + c0.w * c1.y;
        float Cb = c0.z + c0.w * c1.z;
        float Tp = c0.w * c1.w;
        int px = BX*16 + t2i*8 + (ln & 7), py = TY*8 + (ln >> 3);
        int p = py * WW + px;
        float* img = out + (size_t)cam * (HH*WW*3) + (size_t)p * 3;
        img[0] = Cr + Tp;           // bg = (1,1,1)
        img[1] = Cg + Tp;
        img[2] = Cb + Tp;
        out[(size_t)NC*HH*WW*3 + (size_t)cam*(HH*WW) + p] = 1.f - Tp;
    }
}

extern "C" void kernel_launch(void* const* d_in, const int* in_sizes, int n_in,
                              void* d_out, int out_size, void* d_ws, size_t ws_size,
                              hipStream_t stream) {
    const float* w2cs  = (const float*)d_in[0];
    const float* Ks    = (const float*)d_in[1];
    const float* xyz   = (const float*)d_in[2];
    const float* rgb   = (const float*)d_in[3];
    const float* opac  = (const float*)d_in[4];
    const float* scale = (const float*)d_in[5];
    const float* rot   = (const float*)d_in[6];
    float* out = (float*)d_out;

    fused_kernel<<<dim3(RGX, RGY, NC), 256, 0, stream>>>(
        w2cs, Ks, xyz, rgb, opac, scale, rot, out);
}

// Round 6
// 77.804 us; speedup vs baseline: 1.1572x; 1.0292x over previous
//
#include <hip/hip_runtime.h>
#include <math.h>

#define NG 1024
#define NC 2
#define HH 224
#define WW 224
#define TILES_X 28
#define TILES_Y 28
#define EPS2D 0.3f
#define ALPHA_MIN (1.0f/255.0f)
#define ALPHA_MAX 0.999f
#define MAXL 512   // per-tile list capacity (worst observed ~250 incl. superset inflation)
#define LOG2E 1.4426950408889634f

// Best-measured configuration (78.1 us): single dispatch, per 8x8 tile block:
//  1) conservative prefilter of all 1024 gaussians (superset of exact support)
//  2) compact (z_bits<<10)|gid keys into LDS (keys carry full stable order)
//  3) RANK SORT: each thread holds its <=2 keys in regs, counts smaller keys
//     via broadcast LDS reads (no barriers in loop), scatters keys[rank]=key
//     in place. Identical order to bitonic (keys unique).
//  4) full prep in REGISTERS for listed gaussians + EXACT re-cull
//     (alpha>1/255 support bbox from the exact 2D cov diagonal); ballot
//     order-preserving compaction into sorted slots.
//  5) 4 depth-segment waves composite (conic pre-scaled by 0.5*log2e ->
//     exp2) + associative (C,T) merge.
// Measured structural constraint: dur = 40.5us harness poison-fill (268MB @
// 82% HBM peak) + ~5us launch overhead + ~33us latency-bound exec; 2-tile
// amortization (R5), wave-0 sort (R4), and multi-dispatch (R3) all regressed.
__global__ __launch_bounds__(256) void fused_kernel(
        const float* __restrict__ w2cs, const float* __restrict__ Ks,
        const float* __restrict__ xyz, const float* __restrict__ rgb,
        const float* __restrict__ opac, const float* __restrict__ scale,
        const float* __restrict__ rot, float* __restrict__ out) {
    const int cam = blockIdx.z;
    const int TX = blockIdx.x, TY = blockIdx.y;
    const int tid = threadIdx.x;
    const int lane = tid & 63;
    const int wv   = tid >> 6;

    // keys and part are never live simultaneously: keys last read in phase 4
    // prep (before its barrier), part first written after the composite loop.
    __shared__ union {
        unsigned long long keys[MAXL];   // 4096 B
        float4 part[4][64];              // 4096 B
    } shu;
    __shared__ float4 sA[MAXL];          // u, v, ia*0.5*log2e, ib*log2e
    __shared__ float4 sB[MAXL];          // id*0.5*log2e, o, r, g
    __shared__ float  sC[MAXL];          // b (blue)
    __shared__ int    cnt[8];
    __shared__ int    scnt;

    if (tid == 0) scnt = 0;
    __syncthreads();

    const float* vm = w2cs + cam*16;
    const float R00 = vm[0],  R01 = vm[1],  R02 = vm[2],  t0 = vm[3];
    const float R10 = vm[4],  R11 = vm[5],  R12 = vm[6],  t1 = vm[7];
    const float R20 = vm[8],  R21 = vm[9],  R22 = vm[10], t2 = vm[11];
    const float* Kc = Ks + cam*9;
    const float fx = Kc[0], cx = Kc[2], fy = Kc[4], cy = Kc[5];
    const float limx = 1.3f * (0.5f * (float)WW / fx);
    const float limy = 1.3f * (0.5f * (float)HH / fy);

    // ---- phase 1: conservative prefilter, 4 gaussians per thread ----
    #pragma unroll
    for (int k = 0; k < 4; k++) {
        int g = k*256 + tid;
        float X = xyz[g*3], Y = xyz[g*3+1], Z = xyz[g*3+2];
        float pz = R20*X + R21*Y + R22*Z + t2;
        float o  = opac[g];
        float tau = __logf(255.f * o);
        bool cand = (pz > 0.01f) && (pz < 100.f) && (tau > 0.f);
        if (cand) {
            float rz = 1.f / pz;
            float px = R00*X + R01*Y + R02*Z + t0;
            float py = R10*X + R11*Y + R12*Z + t1;
            float uu = fx*px*rz + cx;
            float vv = fy*py*rz + cy;
            float sx = scale[g*3+0], sy = scale[g*3+1], sz = scale[g*3+2];
            float smax = fmaxf(sx, fmaxf(sy, sz));
            float j00 = fx*rz, j11 = fy*rz;
            float j02m = fx*limx*rz, j12m = fy*limy*rz;   // |j02| bound via |tx|<=limx*z
            float abnd = smax*smax*(j00*j00 + j02m*j02m) + EPS2D;  // >= exact a
            float dbnd = smax*smax*(j11*j11 + j12m*j12m) + EPS2D;  // >= exact d
            float rx = sqrtf(2.f*tau*abnd) + 0.01f;
            float ry = sqrtf(2.f*tau*dbnd) + 0.01f;
            int xmin = max((int)ceilf (uu - rx - 0.5f), 0);
            int xmax = min((int)floorf(uu + rx - 0.5f), WW-1);
            int ymin = max((int)ceilf (vv - ry - 0.5f), 0);
            int ymax = min((int)floorf(vv + ry - 0.5f), HH-1);
            cand = (xmin <= xmax) && (ymin <= ymax) &&
                   (TX >= (xmin>>3)) && (TX <= (xmax>>3)) &&
                   (TY >= (ymin>>3)) && (TY <= (ymax>>3));
        }
        unsigned long long m = __ballot(cand);
        int cw = __popcll(m);
        if (cw) {
            int basepos = 0;
            if (lane == 0) basepos = atomicAdd(&scnt, cw);
            basepos = __shfl(basepos, 0);
            if (cand) {
                int pos = basepos + __popcll(m & ((1ull << lane) - 1ull));
                if (pos < MAXL)
                    shu.keys[pos] = ((unsigned long long)__float_as_uint(pz) << 10)
                                  | (unsigned long long)g;
            }
        }
    }
    __syncthreads();
    int n = min(scnt, MAXL);

    // ---- phase 2: rank sort (barrier-free counting; keys unique via gid) ----
    unsigned long long myk0 = (tid       < n) ? shu.keys[tid]       : 0ull;
    unsigned long long myk1 = (tid + 256 < n) ? shu.keys[tid + 256] : 0ull;
    int r0 = 0, r1 = 0;
    #pragma unroll 4
    for (int j = 0; j < n; j++) {
        unsigned long long kj = shu.keys[j];   // wave-uniform -> LDS broadcast
        r0 += (kj < myk0) ? 1 : 0;
        r1 += (kj < myk1) ? 1 : 0;
    }
    __syncthreads();                 // all reads done before in-place scatter
    if (tid       < n) shu.keys[r0] = myk0;
    if (tid + 256 < n) shu.keys[r1] = myk1;
    __syncthreads();

    // ---- phase 3: prep in registers + exact-bbox re-cull ----
    auto prep = [&](int i, float4 &A, float4 &B, float &C) -> bool {
        if (i >= n) return false;
        int g = (int)(shu.keys[i] & 1023ull);

        float qw = rot[g*4+0], qx = rot[g*4+1], qy = rot[g*4+2], qz = rot[g*4+3];
        float qn = rsqrtf(qw*qw + qx*qx + qy*qy + qz*qz);
        qw *= qn; qx *= qn; qy *= qn; qz *= qn;
        float r00 = 1.f - 2.f*(qy*qy + qz*qz), r01 = 2.f*(qx*qy - qw*qz), r02 = 2.f*(qx*qz + qw*qy);
        float r10 = 2.f*(qx*qy + qw*qz), r11 = 1.f - 2.f*(qx*qx + qz*qz), r12 = 2.f*(qy*qz - qw*qx);
        float r20 = 2.f*(qx*qz - qw*qy), r21 = 2.f*(qy*qz + qw*qx), r22 = 1.f - 2.f*(qx*qx + qy*qy);

        float sx = scale[g*3+0], sy = scale[g*3+1], sz = scale[g*3+2];
        float m00 = r00*sx, m01 = r01*sy, m02 = r02*sz;
        float m10 = r10*sx, m11 = r11*sy, m12 = r12*sz;
        float m20 = r20*sx, m21 = r21*sy, m22 = r22*sz;
        float c00 = m00*m00 + m01*m01 + m02*m02;
        float c01 = m00*m10 + m01*m11 + m02*m12;
        float c02 = m00*m20 + m01*m21 + m02*m22;
        float c11 = m10*m10 + m11*m11 + m12*m12;
        float c12 = m10*m20 + m11*m21 + m12*m22;
        float c22 = m20*m20 + m21*m21 + m22*m22;

        float X = xyz[g*3], Y = xyz[g*3+1], Z = xyz[g*3+2];
        float px = R00*X + R01*Y + R02*Z + t0;
        float py = R10*X + R11*Y + R12*Z + t1;
        float pz = R20*X + R21*Y + R22*Z + t2;
        float rz = 1.f / pz;

        float txc = pz * fminf(fmaxf(px*rz, -limx), limx);
        float tyc = pz * fminf(fmaxf(py*rz, -limy), limy);

        float v00 = R00*c00 + R01*c01 + R02*c02;
        float v01 = R00*c01 + R01*c11 + R02*c12;
        float v02 = R00*c02 + R01*c12 + R02*c22;
        float v10 = R10*c00 + R11*c01 + R12*c02;
        float v11 = R10*c01 + R11*c11 + R12*c12;
        float v12 = R10*c02 + R11*c12 + R12*c22;
        float v20 = R20*c00 + R21*c01 + R22*c02;
        float v21 = R20*c01 + R21*c11 + R22*c12;
        float v22 = R20*c02 + R21*c12 + R22*c22;
        float cc00 = v00*R00 + v01*R01 + v02*R02;
        float cc01 = v00*R10 + v01*R11 + v02*R12;
        float cc02 = v00*R20 + v01*R21 + v02*R22;
        float cc11 = v10*R10 + v11*R11 + v12*R12;
        float cc12 = v10*R20 + v11*R21 + v12*R22;
        float cc22 = v20*R20 + v21*R21 + v22*R22;

        float j00 = fx*rz, j02 = -fx*txc*rz*rz;
        float j11 = fy*rz, j12 = -fy*tyc*rz*rz;
        float a  = j00*j00*cc00 + 2.f*j00*j02*cc02 + j02*j02*cc22 + EPS2D;
        float bq = j00*j11*cc01 + j00*j12*cc02 + j02*j11*cc12 + j02*j12*cc22;
        float d  = j11*j11*cc11 + 2.f*j11*j12*cc12 + j12*j12*cc22 + EPS2D;
        float det = a*d - bq*bq;

        if (!((pz > 0.01f) && (pz < 100.f) && (det > 0.f))) return false;

        float o = opac[g];
        float tau = __logf(255.f * o);
        if (!(tau > 0.f)) return false;

        // exact support bbox of {alpha > 1/255} = {sigma <= tau}:
        // half-extents sqrt(2*tau*Sigma'_00), sqrt(2*tau*Sigma'_11) (+margin)
        float hx = sqrtf(2.f*tau*a) + 0.02f;
        float hy = sqrtf(2.f*tau*d) + 0.02f;
        float uu = fx*px*rz + cx;
        float vv = fy*py*rz + cy;
        float xlo = (float)(TX*8) + 0.5f, xhi = (float)(TX*8) + 7.5f;
        float ylo = (float)(TY*8) + 0.5f, yhi = (float)(TY*8) + 7.5f;
        if (uu + hx < xlo || uu - hx > xhi || vv + hy < ylo || vv - hy > yhi)
            return false;

        float idet = 1.f / det;
        A = make_float4(uu, vv, 0.5f*LOG2E*d*idet, -LOG2E*bq*idet);
        B = make_float4(0.5f*LOG2E*a*idet, o, rgb[g*3+0], rgb[g*3+1]);
        C = rgb[g*3+2];
        return true;
    };

    float4 A0, B0, A1, B1; float C0, C1;
    bool kp0 = prep(tid,       A0, B0, C0);
    bool kp1 = prep(tid + 256, A1, B1, C1);

    // order-preserving compaction: segment s = (half<<2)|wv, lane order = i order
    unsigned long long bal0 = __ballot(kp0);
    unsigned long long bal1 = __ballot(kp1);
    if (lane == 0) { cnt[wv] = __popcll(bal0); cnt[4 + wv] = __popcll(bal1); }
    __syncthreads();
    int base0 = 0, base1 = 0, n2 = 0;
    #pragma unroll
    for (int s = 0; s < 8; s++) {
        int cs = cnt[s];
        base0 += (s < wv)     ? cs : 0;
        base1 += (s < 4 + wv) ? cs : 0;
        n2 += cs;
    }
    unsigned long long lt = (1ull << lane) - 1ull;
    int d0 = base0 + __popcll(bal0 & lt);
    int d1 = base1 + __popcll(bal1 & lt);
    if (kp0) { sA[d0] = A0; sB[d0] = B0; sC[d0] = C0; }
    if (kp1) { sA[d1] = A1; sB[d1] = B1; sC[d1] = C1; }
    __syncthreads();

    // ---- phase 4: segmented composite (wave wv = depth segment wv) ----
    const float pxl = (float)(TX*8 + (lane & 7)) + 0.5f;
    const float pyl = (float)(TY*8 + (lane >> 3)) + 0.5f;
    int seglen = (n2 + 3) >> 2;
    int js = wv * seglen;
    int je = min(n2, js + seglen);

    float T = 1.f, cr = 0.f, cg = 0.f, cb = 0.f;
#define CBODY(J) do { \
        float4 ga = sA[J]; float4 gb = sB[J]; float bv = sC[J]; \
        float dx = ga.x - pxl, dy = ga.y - pyl; \
        float sg = ga.z*dx*dx + gb.x*dy*dy + ga.w*dx*dy; \
        float al = fminf(gb.y * exp2f(-sg), ALPHA_MAX); \
        al = (sg >= 0.f && al > ALPHA_MIN) ? al : 0.f; \
        float wgt = al * T; \
        cr += wgt * gb.z; cg += wgt * gb.w; cb += wgt * bv; \
        T -= al * T; \
    } while (0)

    int j = js;
    while (j + 16 <= je) {
        #pragma unroll 4
        for (int q = 0; q < 16; q++) { CBODY(j + q); }
        j += 16;
        if (__all(T < 1e-4f)) break;
    }
    for (; j < je; j++) { CBODY(j); }
#undef CBODY

    shu.part[wv][lane] = make_float4(cr, cg, cb, T);
    __syncthreads();

    if (tid < 64) {
        float4 c0 = shu.part[0][lane];
        float Cr = c0.x, Cg = c0.y, Cb = c0.z, Tp = c0.w;
        #pragma unroll
        for (int s = 1; s < 4; s++) {
            float4 cs = shu.part[s][lane];
            Cr += Tp * cs.x;
            Cg += Tp * cs.y;
            Cb += Tp * cs.z;
            Tp *= cs.w;
        }
        int p = (TY*8 + (lane >> 3)) * WW + TX*8 + (lane & 7);
        float* img = out + (size_t)cam * (HH*WW*3) + (size_t)p * 3;
        img[0] = Cr + Tp;           // bg = (1,1,1)
        img[1] = Cg + Tp;
        img[2] = Cb + Tp;
        out[(size_t)NC*HH*WW*3 + (size_t)cam*(HH*WW) + p] = 1.f - Tp;
    }
}

extern "C" void kernel_launch(void* const* d_in, const int* in_sizes, int n_in,
                              void* d_out, int out_size, void* d_ws, size_t ws_size,
                              hipStream_t stream) {
    const float* w2cs  = (const float*)d_in[0];
    const float* Ks    = (const float*)d_in[1];
    const float* xyz   = (const float*)d_in[2];
    const float* rgb   = (const float*)d_in[3];
    const float* opac  = (const float*)d_in[4];
    const float* scale = (const float*)d_in[5];
    const float* rot   = (const float*)d_in[6];
    float* out = (float*)d_out;

    fused_kernel<<<dim3(TILES_X, TILES_Y, NC), 256, 0, stream>>>(
        w2cs, Ks, xyz, rgb, opac, scale, rot, out);
}